// Round 1
// baseline (1138.219 us; speedup 1.0000x reference)
//
#include <hip/hip_runtime.h>

#define WARMUP  365
#define NSTEP   1825
#define TTOT    2190
#define KERNEL_ 15
#define GRP     15     // group = KERNEL so the conv ring phase is static per group

__global__ __launch_bounds__(64) void hbv_fused_kernel(
    const float* __restrict__ x,       // (TTOT, G, 3): precip, pet, temp
    const float* __restrict__ params,  // (G, 14) in [0,1]
    float* __restrict__ out,           // (NSTEP, G)
    int G)
{
    const int g = blockIdx.x * 64 + threadIdx.x;
    if (g >= G) return;

    // ---- scale parameters to physical ranges ----
    const float* pr = params + (size_t)g * 14;
    const float beta  = 1.0f   + pr[0]  * 5.0f;     // [1, 6]
    const float fc    = 50.0f  + pr[1]  * 950.0f;   // [50, 1000]
    const float k0    = 0.05f  + pr[2]  * 0.85f;    // [0.05, 0.9]
    const float k1    = 0.01f  + pr[3]  * 0.49f;    // [0.01, 0.5]
    const float k2    = 0.001f + pr[4]  * 0.199f;   // [0.001, 0.2]
    const float lp    = 0.2f   + pr[5]  * 0.8f;     // [0.2, 1]
    const float pperc =          pr[6]  * 10.0f;    // [0, 10]
    const float uzl   =          pr[7]  * 100.0f;   // [0, 100]
    const float tt    = -2.5f  + pr[8]  * 5.0f;     // [-2.5, 2.5]
    const float cfmax = 0.5f   + pr[9]  * 9.5f;     // [0.5, 10]
    const float cfr   =          pr[10] * 0.1f;     // [0, 0.1]
    const float cwh   =          pr[11] * 0.2f;     // [0, 0.2]
    const float ra    =          pr[12] * 2.9f;     // [0, 2.9]
    const float rb    =          pr[13] * 6.5f;     // [0, 6.5]

    // ---- unit hydrograph weights (gammaln + aa*log(theta) cancel under
    //      the sum-normalization) ----
    const float aa = fmaxf(ra, 0.0f) + 0.1f;
    const float th = fmaxf(rb, 0.0f) + 0.5f;
    const float inv_th = 1.0f / th;
    float w[KERNEL_];
    float ws = 0.0f;
    #pragma unroll
    for (int k = 0; k < KERNEL_; k++) {
        const float tk = 0.5f + (float)k;
        const float lw = (aa - 1.0f) * __logf(tk) - tk * inv_th;
        w[k] = __expf(lw);
        ws += w[k];
    }
    const float inv_ws = 1.0f / ws;
    #pragma unroll
    for (int k = 0; k < KERNEL_; k++) w[k] *= inv_ws;

    // ---- precomputed reciprocals / products ----
    const float inv_fc   = 1.0f / fc;
    const float inv_lpfc = 1.0f / (lp * fc);
    const float cfrx     = cfr * cfmax;

    // ---- HBV state ----
    float sp  = 0.001f;  // snowpack
    float mw  = 0.001f;  // meltwater
    float sm  = 0.001f;  // soil moisture
    float suz = 0.001f;  // upper zone
    float slz = 0.001f;  // lower zone

    // One HBV step; returns discharge q. Math bit-identical to reference
    // ordering (cfrx*(tt-temp) == -cfrx*dt exactly).
    auto step = [&](float precip, float pet, float temp) -> float {
        const float dt   = temp - tt;
        const float rain = (dt >= 0.0f) ? precip : 0.0f;
        sp += precip - rain;                                  // + snow
        const float melt = fminf(fmaxf(cfmax * dt, 0.0f), sp);
        mw += melt;
        sp -= melt;
        const float refr = fminf(fmaxf(-cfrx * dt, 0.0f), mw);
        sp += refr;
        mw -= refr;
        const float tosoil = fmaxf(mw - cwh * sp, 0.0f);
        mw -= tosoil;
        // sm <= fc invariant, only the upper clamp matters numerically
        const float r   = sm * inv_fc;
        const float wet = fminf(__expf(beta * __logf(r)), 1.0f);
        const float inflow = rain + tosoil;
        const float rech   = inflow * wet;
        sm += inflow - rech;
        const float exc = fmaxf(sm - fc, 0.0f);
        sm -= exc;
        const float ef = fminf(sm * inv_lpfc, 1.0f);
        const float et = fminf(sm, pet * ef);
        sm = fmaxf(sm - et, 1e-5f);
        suz += rech + exc;
        const float perc = fminf(suz, pperc);
        suz -= perc;
        const float q0 = k0 * fmaxf(suz - uzl, 0.0f);
        suz -= q0;
        const float q1 = k1 * suz;
        suz -= q1;
        slz += perc;
        const float q2 = k2 * slz;
        slz -= q2;
        return q0 + q1 + q2;
    };

    // ---- deep software pipeline: 15-step groups, 1 group prefetch ahead ----
    float cur[GRP][3], nxt[GRP][3];

    auto loadg = [&](int t0, float (&dst)[GRP][3]) {
        #pragma unroll
        for (int j = 0; j < GRP; j++) {
            int t = t0 + j;
            if (t > TTOT - 1) t = TTOT - 1;   // clamp (only last main group)
            const float* p = x + ((size_t)t * G + g) * 3;
            dst[j][0] = p[0]; dst[j][1] = p[1]; dst[j][2] = p[2];
        }
    };
    auto advance = [&]() {
        #pragma unroll
        for (int j = 0; j < GRP; j++) {
            cur[j][0] = nxt[j][0]; cur[j][1] = nxt[j][1]; cur[j][2] = nxt[j][2];
        }
    };

    // conv ring: buf[m mod 15] == q_m; all indices compile-time constant
    float buf[KERNEL_];
    #pragma unroll
    for (int k = 0; k < KERNEL_; k++) buf[k] = 0.0f;

    loadg(0, cur);

    // ---- warmup: 24 full groups = steps 0..359 ----
    for (int grp = 0; grp < 24; ++grp) {
        loadg(grp * GRP + GRP, nxt);
        #pragma unroll
        for (int j = 0; j < GRP; j++)
            (void)step(cur[j][0], cur[j][1], cur[j][2]);
        advance();
    }
    // cur now holds times 360..374
    loadg(375, nxt);
    #pragma unroll
    for (int j = 0; j < 5; j++)           // warmup steps 360..364
        (void)step(cur[j][0], cur[j][1], cur[j][2]);
    #pragma unroll
    for (int j = 0; j < 10; j++) {        // main steps m = 0..9, ring pos = j
        const float q = step(cur[5 + j][0], cur[5 + j][1], cur[5 + j][2]);
        buf[j] = q;
        float acc = 0.0f;
        #pragma unroll
        for (int k = 0; k < KERNEL_; k++)
            acc = fmaf(w[k], buf[(j - k + KERNEL_) % KERNEL_], acc);
        __builtin_nontemporal_store(acc, out + (size_t)j * G + g);
    }
    advance();                            // cur = times 375..389

    // ---- main: 121 full groups (steps 375..2189); ring phase is 10 at the
    //      top of every group (10 + 15*grp ≡ 10 mod 15) → static indices ----
    for (int grp = 0; grp < 121; ++grp) {
        const int t0 = 375 + grp * GRP;
        const int m0 = t0 - WARMUP;       // 10 + 15*grp
        loadg(t0 + GRP, nxt);             // last group clamps to t = 2189
        #pragma unroll
        for (int j = 0; j < GRP; j++) {
            const float q = step(cur[j][0], cur[j][1], cur[j][2]);
            const int p = (10 + j) % KERNEL_;     // compile-time constant
            buf[p] = q;
            float acc = 0.0f;
            #pragma unroll
            for (int k = 0; k < KERNEL_; k++)
                acc = fmaf(w[k], buf[(p - k + KERNEL_) % KERNEL_], acc);
            __builtin_nontemporal_store(acc, out + (size_t)(m0 + j) * G + g);
        }
        advance();
    }
}

extern "C" void kernel_launch(void* const* d_in, const int* in_sizes, int n_in,
                              void* d_out, int out_size, void* d_ws, size_t ws_size,
                              hipStream_t stream) {
    const float* x      = (const float*)d_in[0];   // (2190, G, 3) f32
    const float* params = (const float*)d_in[1];   // (G, 14) f32
    float* out = (float*)d_out;                    // (1825, G, 1) f32
    const int G = in_sizes[1] / 14;
    const int blocks = (G + 63) / 64;
    hbv_fused_kernel<<<blocks, 64, 0, stream>>>(x, params, out, G);
}

// Round 2
// 610.845 us; speedup vs baseline: 1.8634x; 1.8634x over previous
//
#include <hip/hip_runtime.h>

#define WARMUP  365
#define NSTEP   1825
#define TTOT    2190
#define KERNEL_ 15
#define CH      15      // steps per chunk == conv kernel -> static ring phase
#define NCH     3       // LDS ring depth in chunks (45-step prefetch)
#define SLOTF   256     // floats per timestep slot (1024 B staged, 768 valid)
#define NCHUNK  146     // 2190 / 15

// Counted wait: guarantee the oldest chunk's 15 loads have landed.
// In every phase >= CH*(NCH-1) = 30 vmem entries are younger than them.
#define WAIT_RING() asm volatile("s_waitcnt vmcnt(30)" ::: "memory")

typedef __attribute__((address_space(1))) const void g_void;
typedef __attribute__((address_space(3))) void l_void;

__global__ __launch_bounds__(64) void hbv_fused_kernel(
    const float* __restrict__ x,       // (TTOT, G, 3): precip, pet, temp
    const float* __restrict__ params,  // (G, 14) in [0,1]
    float* __restrict__ out,           // (NSTEP, G)
    int G)
{
    __shared__ float lds[NCH * CH * SLOTF];   // 46080 B

    const int lane = threadIdx.x;
    const int g0   = blockIdx.x * 64;
    const int g    = g0 + lane;
    if (g >= G) return;

    // ---- scale parameters to physical ranges ----
    const float* pr = params + (size_t)g * 14;
    const float beta  = 1.0f   + pr[0]  * 5.0f;
    const float fc    = 50.0f  + pr[1]  * 950.0f;
    const float k0    = 0.05f  + pr[2]  * 0.85f;
    const float k1    = 0.01f  + pr[3]  * 0.49f;
    const float k2    = 0.001f + pr[4]  * 0.199f;
    const float lp    = 0.2f   + pr[5]  * 0.8f;
    const float pperc =          pr[6]  * 10.0f;
    const float uzl   =          pr[7]  * 100.0f;
    const float tt    = -2.5f  + pr[8]  * 5.0f;
    const float cfmax = 0.5f   + pr[9]  * 9.5f;
    const float cfr   =          pr[10] * 0.1f;
    const float cwh   =          pr[11] * 0.2f;
    const float ra    =          pr[12] * 2.9f;
    const float rb    =          pr[13] * 6.5f;

    // ---- unit hydrograph weights (gammaln + aa*log(theta) cancel under
    //      the sum-normalization) ----
    const float aa = fmaxf(ra, 0.0f) + 0.1f;
    const float th = fmaxf(rb, 0.0f) + 0.5f;
    const float inv_th = 1.0f / th;
    float w[KERNEL_];
    float ws = 0.0f;
    #pragma unroll
    for (int k = 0; k < KERNEL_; k++) {
        const float tk = 0.5f + (float)k;
        const float lw = (aa - 1.0f) * __logf(tk) - tk * inv_th;
        w[k] = __expf(lw);
        ws += w[k];
    }
    const float inv_ws = 1.0f / ws;
    #pragma unroll
    for (int k = 0; k < KERNEL_; k++) w[k] *= inv_ws;

    // ---- precomputed reciprocals / products ----
    const float inv_fc   = 1.0f / fc;
    const float inv_lpfc = 1.0f / (lp * fc);
    const float cfrx     = cfr * cfmax;

    // ---- HBV state ----
    float sp  = 0.001f;
    float mw  = 0.001f;
    float sm  = 0.001f;
    float suz = 0.001f;
    float slz = 0.001f;

    // One HBV step (bit-identical ordering to reference)
    auto step = [&](float precip, float pet, float temp) -> float {
        const float dt   = temp - tt;
        const float rain = (dt >= 0.0f) ? precip : 0.0f;
        sp += precip - rain;
        const float melt = fminf(fmaxf(cfmax * dt, 0.0f), sp);
        mw += melt;
        sp -= melt;
        const float refr = fminf(fmaxf(-cfrx * dt, 0.0f), mw);
        sp += refr;
        mw -= refr;
        const float tosoil = fmaxf(mw - cwh * sp, 0.0f);
        mw -= tosoil;
        const float r   = sm * inv_fc;
        const float wet = fminf(__expf(beta * __logf(r)), 1.0f);
        const float inflow = rain + tosoil;
        const float rech   = inflow * wet;
        sm += inflow - rech;
        const float exc = fmaxf(sm - fc, 0.0f);
        sm -= exc;
        const float ef = fminf(sm * inv_lpfc, 1.0f);
        const float et = fminf(sm, pet * ef);
        sm = fmaxf(sm - et, 1e-5f);
        suz += rech + exc;
        const float perc = fminf(suz, pperc);
        suz -= perc;
        const float q0 = k0 * fmaxf(suz - uzl, 0.0f);
        suz -= q0;
        const float q1 = k1 * suz;
        suz -= q1;
        slz += perc;
        const float q2 = k2 * slz;
        slz -= q2;
        return q0 + q1 + q2;
    };

    // ---- async staging: one wave-wide dwordx4 per timestep (1024 B,
    //      768 valid; lanes 48-63 duplicate-load — same cache lines) ----
    const unsigned rowb   = (unsigned)G * 12u;              // bytes per timestep row-chunk stride
    const unsigned maxoff = (unsigned)TTOT * rowb - 16u;    // OOB clamp (dup data, never consumed)
    const unsigned roff   = (unsigned)g0 * 12u + (unsigned)lane * 16u;
    const char* xb = (const char*)x;

    // refill slot with CH timesteps starting at per-lane byte offset off0
    auto refill = [&](int slot, unsigned off0) {
        unsigned off = off0;
        #pragma unroll
        for (int j = 0; j < CH; ++j) {
            const unsigned o = off > maxoff ? maxoff : off;
            __builtin_amdgcn_global_load_lds(
                (g_void*)(xb + o),
                (l_void*)&lds[(slot * CH + j) * SLOTF],
                16, 0, 0);
            off += rowb;
        }
    };
    auto fetch3 = [&](int slot, int j, float& p, float& e, float& t) {
        const float* s = &lds[(slot * CH + j) * SLOTF + lane * 3];
        p = s[0]; e = s[1]; t = s[2];   // stride-3 -> 2 lanes/bank, conflict-free
    };

    // conv ring: buf[m mod 15] == q_m, all indices compile-time constant
    float buf[KERNEL_];
    #pragma unroll
    for (int k = 0; k < KERNEL_; k++) buf[k] = 0.0f;

    // ---- prologue: fill the ring (45 loads in flight) ----
    unsigned offnext = roff;                       // chunk 0 start
    refill(0, offnext); offnext += (unsigned)CH * rowb;
    refill(1, offnext); offnext += (unsigned)CH * rowb;
    refill(2, offnext); offnext += (unsigned)CH * rowb;

    int slot = 0;

    // ---- warmup chunks 0..23 (t = 0..359) ----
    for (int c = 0; c < 24; ++c) {
        WAIT_RING();
        #pragma unroll
        for (int j = 0; j < CH; ++j) {
            float p, e, t; fetch3(slot, j, p, e, t);
            (void)step(p, e, t);
        }
        refill(slot, offnext); offnext += (unsigned)CH * rowb;
        slot = (slot == NCH - 1) ? 0 : slot + 1;
    }

    // ---- chunk 24 (t = 360..374): 5 warmup steps + main m = 0..9 ----
    {
        WAIT_RING();
        #pragma unroll
        for (int j = 0; j < 5; ++j) {
            float p, e, t; fetch3(slot, j, p, e, t);
            (void)step(p, e, t);
        }
        #pragma unroll
        for (int j = 0; j < 10; ++j) {             // ring pos = j
            float p, e, t; fetch3(slot, 5 + j, p, e, t);
            const float q = step(p, e, t);
            buf[j] = q;
            float acc = 0.0f;
            #pragma unroll
            for (int k = 0; k < KERNEL_; ++k)
                acc = fmaf(w[k], buf[(j - k + KERNEL_) % KERNEL_], acc);
            out[(size_t)j * G + g] = acc;
        }
        refill(slot, offnext); offnext += (unsigned)CH * rowb;
        slot = (slot == NCH - 1) ? 0 : slot + 1;
    }

    // ---- main chunks 25..145 (t = 375..2189); ring phase 10 at j=0 ----
    int m0 = 10;                                   // 15*25 - 365
    for (int c = 25; c < NCHUNK; ++c) {
        WAIT_RING();
        #pragma unroll
        for (int j = 0; j < CH; ++j) {
            float p, e, t; fetch3(slot, j, p, e, t);
            const float q = step(p, e, t);
            const int pos = (10 + j) % KERNEL_;    // compile-time constant
            buf[pos] = q;
            float acc = 0.0f;
            #pragma unroll
            for (int k = 0; k < KERNEL_; ++k)
                acc = fmaf(w[k], buf[(pos - k + KERNEL_) % KERNEL_], acc);
            out[(size_t)(m0 + j) * G + g] = acc;
        }
        // tail refills auto-clamp past t=2189 (junk slots never consumed)
        refill(slot, offnext); offnext += (unsigned)CH * rowb;
        slot = (slot == NCH - 1) ? 0 : slot + 1;
        m0 += CH;
    }
}

extern "C" void kernel_launch(void* const* d_in, const int* in_sizes, int n_in,
                              void* d_out, int out_size, void* d_ws, size_t ws_size,
                              hipStream_t stream) {
    const float* x      = (const float*)d_in[0];   // (2190, G, 3) f32
    const float* params = (const float*)d_in[1];   // (G, 14) f32
    float* out = (float*)d_out;                    // (1825, G, 1) f32
    const int G = in_sizes[1] / 14;
    const int blocks = (G + 63) / 64;
    hbv_fused_kernel<<<blocks, 64, 0, stream>>>(x, params, out, G);
}

// Round 4
// 590.693 us; speedup vs baseline: 1.9269x; 1.0341x over previous
//
#include <hip/hip_runtime.h>

#define WARMUP  365
#define NSTEP   1825
#define TTOT    2190
#define KERNEL_ 15
#define CH      15      // steps per chunk == conv kernel -> static ring phase
#define ROWF    256     // floats per staged raw row (1024 B; 768 B valid)
#define NCHUNK  146     // 2190 / 15

typedef __attribute__((address_space(1))) const void g_void;
typedef __attribute__((address_space(3))) void l_void;

__global__ __launch_bounds__(128) void hbv_fused_kernel(
    const float* __restrict__ x,       // (TTOT, G, 3): precip, pet, temp
    const float* __restrict__ params,  // (G, 14) in [0,1]
    float* __restrict__ out,           // (NSTEP, G)
    int G)
{
    // raw: staged global rows (width-16 global_load_lds, round-2-proven).
    // pre4: double-buffered (rain, snow, mr, pet) float4 per cell (wave1 -> wave0).
    // qring: double-buffered discharge handoff (wave0 -> wave1).
    __shared__ __align__(16) float  raw  [3 * CH * ROWF];   // 46080 B
    __shared__ __align__(16) float4 pre4 [2 * CH * 64];     // 30720 B
    __shared__ __align__(16) float  qring[2 * CH * 64];     //  7680 B

    const int tid  = threadIdx.x;
    const int wv   = tid >> 6;         // 0 = compute wave, 1 = helper wave
    const int lane = tid & 63;
    const int g0   = blockIdx.x * 64;
    const int g    = g0 + lane;
    if (g >= G) return;                // partial-wave exit; both waves stay alive

    // ---- scale parameters ----
    const float* pr = params + (size_t)g * 14;
    const float beta  = 1.0f   + pr[0]  * 5.0f;
    const float fc    = 50.0f  + pr[1]  * 950.0f;
    const float k0    = 0.05f  + pr[2]  * 0.85f;
    const float k1    = 0.01f  + pr[3]  * 0.49f;
    const float k2    = 0.001f + pr[4]  * 0.199f;
    const float lp    = 0.2f   + pr[5]  * 0.8f;
    const float pperc =          pr[6]  * 10.0f;
    const float uzl   =          pr[7]  * 100.0f;
    const float tt    = -2.5f  + pr[8]  * 5.0f;
    const float cfmax = 0.5f   + pr[9]  * 9.5f;
    const float cfr   =          pr[10] * 0.1f;
    const float cwh   =          pr[11] * 0.2f;
    const float ra    =          pr[12] * 2.9f;
    const float rb    =          pr[13] * 6.5f;

    const float inv_fc   = 1.0f / fc;
    const float inv_lpfc = 1.0f / (lp * fc);
    const float cfrx     = cfr * cfmax;

    // ---- conv weights (gammaln + aa*log(theta) cancel under normalization) ----
    const float aa = fmaxf(ra, 0.0f) + 0.1f;
    const float th = fmaxf(rb, 0.0f) + 0.5f;
    const float inv_th = 1.0f / th;
    float w[KERNEL_];
    float ws = 0.0f;
    #pragma unroll
    for (int k = 0; k < KERNEL_; k++) {
        const float tk = 0.5f + (float)k;
        w[k] = __expf((aa - 1.0f) * __logf(tk) - tk * inv_th);
        ws += w[k];
    }
    const float inv_ws = 1.0f / ws;
    #pragma unroll
    for (int k = 0; k < KERNEL_; k++) w[k] *= inv_ws;

    // ---- HBV state (wave0) ----
    float sp = 0.001f, mw = 0.001f, sm = 0.001f, suz = 0.001f, slz = 0.001f;

    // ---- conv sliding window (wave1), cbuf[m mod 15] == q_m ----
    float cbuf[KERNEL_];
    #pragma unroll
    for (int k = 0; k < KERNEL_; k++) cbuf[k] = 0.0f;

    // ---- staging (wave1): width-16 global_load_lds, exactly round-2's
    //      proven pattern (1024 B/row staged, 768 valid; clamp dups) ----
    const unsigned rowb   = (unsigned)G * 12u;
    const unsigned maxoff = (unsigned)TTOT * rowb - 16u;
    const unsigned roff   = (unsigned)g0 * 12u + (unsigned)lane * 16u;
    const char* xb = (const char*)x;

    auto refill = [&](int s, int h) {   // stage chunk h into raw slot s
        const unsigned hb = (unsigned)(h * CH) * rowb + roff;
        #pragma unroll
        for (int j = 0; j < CH; ++j) {
            unsigned off = hb + (unsigned)j * rowb;
            off = off > maxoff ? maxoff : off;   // global tail clamp only
            __builtin_amdgcn_global_load_lds(
                (g_void*)(xb + off),
                (l_void*)&raw[(s * CH + j) * ROWF],   // uniform base + lane*16
                16, 0, 0);
        }
    };

    // input transform raw slot s -> pre4 buffer b (separate array: no aliasing).
    // mr = meltcap - refrcap (disjoint support) -> bitwise-exact recovery.
    auto precompute = [&](int s, int b) {
        const float* rowbase = &raw[s * CH * ROWF];
        float4* dst = &pre4[b * (CH * 64) + lane];
        #pragma unroll
        for (int j = 0; j < CH; ++j) {
            const float* row = rowbase + j * ROWF + lane * 3;
            const float p = row[0];
            const float e = row[1];
            const float t = row[2];
            const float dt   = t - tt;
            const float rain = (dt >= 0.0f) ? p : 0.0f;
            float4 o;
            o.x = rain;
            o.y = p - rain;
            o.z = fmaxf(cfmax * dt, 0.0f) - fmaxf(-cfrx * dt, 0.0f);
            o.w = e;
            dst[j * 64] = o;
        }
    };

    // ---- prologue: stage chunks 0,1; drain; precompute chunk 0 -> pre4[0] ----
    if (wv == 1) { refill(0, 0); refill(1, 1); }
    __syncthreads();
    if (wv == 1) precompute(0, 0);

    float* outp = out + g;   // wave1 output cursor (set properly at h==24)

    // ---- pipeline: iter c: w0 steps chunk c (reads pre4[c&1], writes
    //      qring[c&1]) | w1 refills chunk c+2, precomputes chunk c+1 into
    //      pre4[(c+1)&1], convolves chunk c-1 from qring[(c-1)&1] ----
    for (int c = 0; c <= NCHUNK; ++c) {
        __syncthreads();   // drains each wave's vmcnt/lgkm; publishes LDS

        if (wv == 0) {
            if (c < NCHUNK) {
                const float4* pv = &pre4[(c & 1) * (CH * 64) + lane];
                float* qw = &qring[(c & 1) * (CH * 64) + lane];
                #pragma unroll
                for (int j = 0; j < CH; ++j) {
                    const float4 v = pv[j * 64];
                    const float rain = v.x, snow = v.y, mr = v.z, pet = v.w;
                    sp += snow;
                    const float melt = fminf(fmaxf(mr, 0.0f), sp);
                    mw += melt; sp -= melt;
                    const float refr = fminf(fmaxf(-mr, 0.0f), mw);
                    sp += refr; mw -= refr;
                    const float tosoil = fmaxf(mw - cwh * sp, 0.0f);
                    mw -= tosoil;
                    const float r   = sm * inv_fc;
                    const float wet = fminf(__expf(beta * __logf(r)), 1.0f);
                    const float inflow = rain + tosoil;
                    const float rech   = inflow * wet;
                    sm += inflow - rech;
                    const float exc = fmaxf(sm - fc, 0.0f);
                    sm -= exc;
                    const float ef = fminf(sm * inv_lpfc, 1.0f);
                    const float et = fminf(sm, pet * ef);
                    sm = fmaxf(sm - et, 1e-5f);
                    suz += rech + exc;
                    const float perc = fminf(suz, pperc);
                    suz -= perc;
                    const float q0 = k0 * fmaxf(suz - uzl, 0.0f);
                    suz -= q0;
                    const float q1 = k1 * suz;
                    suz -= q1;
                    slz += perc;
                    const float q2 = k2 * slz;
                    slz -= q2;
                    qw[j * 64] = q0 + q1 + q2;
                }
            }
        } else {
            if (c + 2 < NCHUNK) refill((c + 2) % 3, c + 2);          // earliest issue
            if (c + 1 < NCHUNK) precompute((c + 1) % 3, (c + 1) & 1);
            const int h = c - 1;                  // chunk to convolve
            if (h >= 24) {
                const float* qs = &qring[(h & 1) * (CH * 64) + lane];
                if (h == 24) {
                    // main outputs m = 0..9 live at j = 5..14; older taps zero
                    #pragma unroll
                    for (int j = 5; j < CH; ++j) {
                        const int m = j - 5;              // ring pos = m
                        cbuf[m] = qs[j * 64];
                        float acc = 0.0f;
                        #pragma unroll
                        for (int k = 0; k < KERNEL_; ++k)
                            acc = fmaf(w[k], cbuf[((m - k) % 15 + 15) % 15], acc);
                        out[(size_t)m * G + g] = acc;
                    }
                    outp = out + (size_t)10 * G + g;
                } else {
                    // chunk h >= 25: m0 = 15h-365, ring phase (j+10)%15 static
                    #pragma unroll
                    for (int j = 0; j < CH; ++j) {
                        cbuf[(j + 10) % 15] = qs[j * 64];
                        float acc = 0.0f;
                        #pragma unroll
                        for (int k = 0; k < KERNEL_; ++k)
                            acc = fmaf(w[k], cbuf[((j + 10 - k) % 15 + 15) % 15], acc);
                        outp[(size_t)j * G] = acc;
                    }
                    outp += (size_t)CH * G;
                }
            }
        }
    }
}

extern "C" void kernel_launch(void* const* d_in, const int* in_sizes, int n_in,
                              void* d_out, int out_size, void* d_ws, size_t ws_size,
                              hipStream_t stream) {
    const float* x      = (const float*)d_in[0];   // (2190, G, 3) f32
    const float* params = (const float*)d_in[1];   // (G, 14) f32
    float* out = (float*)d_out;                    // (1825, G, 1) f32
    const int G = in_sizes[1] / 14;
    const int blocks = (G + 63) / 64;
    hbv_fused_kernel<<<blocks, 128, 0, stream>>>(x, params, out, G);
}